// Round 4
// baseline (149.004 us; speedup 1.0000x reference)
//
#include <hip/hip_runtime.h>
#include <hip/hip_fp16.h>

// GraphConv: out = segment_sum(w * X[src] -> dst) @ W + b
// = gather of w * (X@W)[src] per dst (matmul distributes over segment-sum).
// Round 13: (a) revert r12's hipMemsetAsync -> zero_kernel (fill dispatch
// cost +2.3us). (b) Vectorize gather's Y reads 8x: lane = (row g = lane>>3,
// channel-octet c8 = lane&7); one dwordx4 (8 fp16) per lane covers 8 records
// per wave-instruction (16 cache lines / vmcnt item, 2-batch unroll = 32
// lines in flight at 1/8 the load-instruction count). Per-vertex acc[8]
// reduced by 3-round shfl_xor butterfly over g; g==0 lanes write 2x float4.
// Discriminates issue/MLP-limited vs L3-BW-limited gather.
//
// V=100000, E=1250000, C=64, fp32 in/out.

constexpr int V = 100000;
constexpr int E = 1250000;
constexpr int C = 64;

constexpr int NBKT = 1024;        // dst buckets
constexpr int VB   = 98;          // vertices per bucket (1024*98 >= V)
constexpr int BCAP = 1536;        // records per bucket (mean 1221, +9 sigma)
constexpr int FL   = 8;           // LDS staging slots per bucket in bin role
constexpr int OVF_CAP = 16384;

// ---------------- workspace layout (bytes) ----------------
constexpr size_t Y_OFF    = 0;           // V*C*2 = 12,800,000 (fp16)
constexpr size_t BIN_OFF  = 12800000;    // NBKT*BCAP*8 = 12,582,912
constexpr size_t GCNT_OFF = 25382912;    // NBKT*4 = 4,096
constexpr size_t OC_OFF   = 25387008;    // 16  (contiguous after gcnt)
constexpr size_t OVF_OFF  = 25387024;    // OVF_CAP*16 = 262,144
constexpr size_t WS_NEW   = 25649168;

using bf16x8 = __attribute__((ext_vector_type(8))) short;
using f32x4  = __attribute__((ext_vector_type(4))) float;

__device__ __forceinline__ short f2bf(float x) {          // RNE float->bf16 bits
    unsigned u = __float_as_uint(x);
    unsigned r = u + 0x7fffu + ((u >> 16) & 1u);
    return (short)(r >> 16);
}
__device__ __forceinline__ float bf2f(short h) {
    return __uint_as_float(((unsigned)(unsigned short)h) << 16);
}

__device__ __forceinline__ void h8_to_f8(float4 v, float* o) {   // 8 fp16 -> 8 fp32
    union { float4 f4; __half2 h2[4]; } U; U.f4 = v;
    float2 a0 = __half22float2(U.h2[0]);
    float2 a1 = __half22float2(U.h2[1]);
    float2 a2 = __half22float2(U.h2[2]);
    float2 a3 = __half22float2(U.h2[3]);
    o[0] = a0.x; o[1] = a0.y; o[2] = a1.x; o[3] = a1.y;
    o[4] = a2.x; o[5] = a2.y; o[6] = a3.x; o[7] = a3.y;
}

// ---------------------------------------------------------------------------
// Tiny zero kernel: gcnt (1024 ints) + oc. ~1.5us, stream-ordered before the
// fused kernel (measured faster than a hipMemsetAsync fill dispatch, r12).
// ---------------------------------------------------------------------------
__global__ __launch_bounds__(256) void zero_kernel(int* __restrict__ gcnt,
                                                   int* __restrict__ oc) {
    int i = threadIdx.x;
    #pragma unroll
    for (int j = 0; j < NBKT / 256; ++j) gcnt[i + j * 256] = 0;
    if (i == 0) *oc = 0;
}

// ---------------------------------------------------------------------------
// Fused XW + bin kernel (r10, verified). 512-thread blocks, grid = 261x5:
// slots 0-2 -> xw role (782 blocks x 8 waves = 6256 chunks >= 6250),
// slots 3-4 -> bin role (512 blocks). Interleave keeps both roles resident
// on every CU so the bin phase hides behind xw.
// ---------------------------------------------------------------------------
constexpr int FUSE_T    = 512;
constexpr int XWB       = 782;           // xw role blocks
constexpr int BINB      = 512;           // bin role blocks
constexpr int FUSE_GRID = 261 * 5;       // 1305 (last group partially idle)

__global__ __launch_bounds__(FUSE_T) void xwbin_kernel(
        const float* __restrict__ X,
        const float* __restrict__ W,
        __half*      __restrict__ Y,
        const int*   __restrict__ esrc,
        const int*   __restrict__ edst,
        const float* __restrict__ ew,
        int*  __restrict__ gcnt,
        int2* __restrict__ binned,
        int*  __restrict__ oc,
        int4* __restrict__ ovf) {
    __shared__ union {
        struct { short Whi[64 * 72]; short Wlo[64 * 72]; } xw;   // 18.4 KB
        struct { int2 stage[NBKT][FL]; int lcnt[NBKT]; } bin;    // 68 KB
    } u;

    const int grp  = blockIdx.x / 5;
    const int slot = blockIdx.x % 5;

    if (slot < 3) {
        // ------------------------------ XW role ------------------------------
        const int xb = grp * 3 + slot;
        if (xb >= XWB) return;

        for (int idx = threadIdx.x; idx < 4096; idx += FUSE_T) {
            int k = idx >> 6, c = idx & 63;
            float w  = W[idx];
            short hi = f2bf(w);
            short lo = f2bf(w - bf2f(hi));
            u.xw.Whi[c * 72 + k] = hi;
            u.xw.Wlo[c * 72 + k] = lo;
        }
        __syncthreads();

        const int wave = threadIdx.x >> 6;       // 0..7
        const int lane = threadIdx.x & 63;
        const int m = lane & 15;
        const int q = lane >> 4;

        bf16x8 bhi[4][2], blo[4][2];
        #pragma unroll
        for (int t = 0; t < 4; ++t)
            #pragma unroll
            for (int h = 0; h < 2; ++h) {
                int o = (t * 16 + m) * 72 + h * 32 + q * 8;
                bhi[t][h] = *(const bf16x8*)&u.xw.Whi[o];
                blo[t][h] = *(const bf16x8*)&u.xw.Wlo[o];
            }

        const int chunk = xb * 8 + wave;
        if (chunk >= V / 16) return;
        {
            const float* xp = X + (chunk * 16 + m) * 64 + q * 8;
            bf16x8 ahi[2], alo[2];
            #pragma unroll
            for (int h = 0; h < 2; ++h) {
                float4 f0 = *(const float4*)(xp + h * 32);
                float4 f1 = *(const float4*)(xp + h * 32 + 4);
                float f[8] = {f0.x, f0.y, f0.z, f0.w, f1.x, f1.y, f1.z, f1.w};
                #pragma unroll
                for (int j = 0; j < 8; ++j) {
                    short hi = f2bf(f[j]);
                    ahi[h][j] = hi;
                    alo[h][j] = f2bf(f[j] - bf2f(hi));
                }
            }
            #pragma unroll
            for (int t = 0; t < 4; ++t) {
                f32x4 acc = {0.f, 0.f, 0.f, 0.f};
                #pragma unroll
                for (int h = 0; h < 2; ++h) {
                    acc = __builtin_amdgcn_mfma_f32_16x16x32_bf16(ahi[h], bhi[t][h], acc, 0, 0, 0);
                    acc = __builtin_amdgcn_mfma_f32_16x16x32_bf16(alo[h], bhi[t][h], acc, 0, 0, 0);
                    acc = __builtin_amdgcn_mfma_f32_16x16x32_bf16(ahi[h], blo[t][h], acc, 0, 0, 0);
                }
                #pragma unroll
                for (int i = 0; i < 4; ++i) {
                    int row = chunk * 16 + q * 4 + i;
                    Y[row * 64 + t * 16 + m] = __float2half(acc[i]);
                }
            }
        }
    } else {
        // ------------------------------ bin role -----------------------------
        const int bb = grp * 2 + (slot - 3);
        if (bb >= BINB) return;

        for (int i = threadIdx.x; i < NBKT; i += FUSE_T) u.bin.lcnt[i] = 0;
        __syncthreads();

        const int iters = (E + BINB * FUSE_T - 1) / (BINB * FUSE_T);   // 5
        for (int it = 0; it < iters; ++it) {
            int e = (it * BINB + bb) * FUSE_T + threadIdx.x;
            if (e < E) {
                int d = edst[e];
                int s = esrc[e];
                float w = ew[e];
                int bkt = d / VB;
                int ld  = d - bkt * VB;
                int2 rec = make_int2((ld << 17) | s, __float_as_int(w));
                int pos = atomicAdd(&u.bin.lcnt[bkt], 1);
                if (pos < FL) {
                    u.bin.stage[bkt][pos] = rec;
                } else {                              // staging spill (~0.1%)
                    int g = atomicAdd(&gcnt[bkt], 1);
                    if (g < BCAP) binned[bkt * BCAP + g] = rec;
                    else { int p = atomicAdd(oc, 1);
                           if (p < OVF_CAP) ovf[p] = make_int4(s, d, __float_as_int(w), 0); }
                }
            }
        }
        __syncthreads();
        // final flush: one thread per bucket — contiguous burst each
        for (int b = threadIdx.x; b < NBKT; b += FUSE_T) {
            int n = u.bin.lcnt[b]; n = n < FL ? n : FL;
            if (n > 0) {
                int g = atomicAdd(&gcnt[b], n);
                for (int i = 0; i < n; ++i) {
                    int gi = g + i;
                    int2 r = u.bin.stage[b][i];
                    if (gi < BCAP) binned[b * BCAP + gi] = r;
                    else { int s = r.x & 0x1FFFF; int ld = r.x >> 17;
                           int p = atomicAdd(oc, 1);
                           if (p < OVF_CAP) ovf[p] = make_int4(s, b * VB + ld, r.y, 0); }
                }
            }
        }
    }
}

// ---------------------------------------------------------------------------
// Bucket gather (r13): counting sort unchanged; gather phase vectorized.
// Lane = (g = lane>>3 row-slot, c8 = lane&7 channel-octet). One dwordx4
// (8 fp16) per lane -> 8 records per wave-instruction, 2-batch unroll.
// Per-vertex acc[8] (channels c8*8..+7 for row-subset g); butterfly reduce
// over g (xor 8/16/32); g==0 lanes write 2x float4 with fused bias.
// ---------------------------------------------------------------------------
__global__ __launch_bounds__(512) void bucket_gather_kernel(const int*  __restrict__ gcnt,
                                                            const int2* __restrict__ binned,
                                                            const int*  __restrict__ oc,
                                                            const int4* __restrict__ ovf,
                                                            const __half* __restrict__ Y,
                                                            const float* __restrict__ bias,
                                                            float* __restrict__ out) {
    __shared__ int2 raw[BCAP];           // 12 KB
    __shared__ int2 sorted[BCAP];        // 12 KB
    __shared__ int  cnt[VB];
    __shared__ int  pre[VB];
    __shared__ int  cur[VB];
    __shared__ int  buf[128];

    const int tid = threadIdx.x;
    const int b   = blockIdx.x;
    int n = gcnt[b]; n = n < BCAP ? n : BCAP;

    for (int i = tid; i < VB; i += 512) cnt[i] = 0;
    __syncthreads();

    const int2* src = binned + b * BCAP;
    for (int i = tid; i < n; i += 512) {
        int2 r = src[i];
        raw[i] = r;
        atomicAdd(&cnt[r.x >> 17], 1);
    }
    __syncthreads();

    // exclusive scan of cnt[0..VB) over first 128 threads (VB <= 128)
    int x = 0;
    if (tid < 128) { x = (tid < VB) ? cnt[tid] : 0; buf[tid] = x; }
    __syncthreads();
    #pragma unroll
    for (int ofs = 1; ofs < 128; ofs <<= 1) {
        int t = 0;
        if (tid < 128 && tid >= ofs) t = buf[tid - ofs];
        __syncthreads();
        if (tid < 128) buf[tid] += t;
        __syncthreads();
    }
    if (tid < VB) { int ex = buf[tid] - x; pre[tid] = ex; cur[tid] = ex; }
    __syncthreads();

    for (int i = tid; i < n; i += 512) {
        int2 r = raw[i];
        int ld = r.x >> 17;
        int p = atomicAdd(&cur[ld], 1);
        sorted[p] = r;
    }
    __syncthreads();

    const int lane = tid & 63;
    const int wv   = tid >> 6;           // 0..7
    const int g    = lane >> 3;          // 0..7 row-slot
    const int c8   = lane & 7;           // 0..7 channel-octet

    float4 bb0 = *(const float4*)(bias + c8 * 8);
    float4 bb1 = *(const float4*)(bias + c8 * 8 + 4);
    int ovn = *oc; ovn = ovn < OVF_CAP ? ovn : OVF_CAP;   // expected 0

    for (int ld = wv; ld < VB; ld += 8) {
        int v = b * VB + ld;
        if (v >= V) break;
        int beg = pre[ld];
        int end = beg + cnt[ld];
        float accv[8];
        #pragma unroll
        for (int j = 0; j < 8; ++j) accv[j] = 0.f;

        int i = beg;
        for (; i + 16 <= end; i += 16) {          // 2 batches of 8 in flight
            int2 ra = sorted[i + g];
            int2 rb = sorted[i + 8 + g];
            float4 ya = *(const float4*)(Y + (ra.x & 0x1FFFF) * C + c8 * 8);
            float4 yb = *(const float4*)(Y + (rb.x & 0x1FFFF) * C + c8 * 8);
            float wa = __int_as_float(ra.y);
            float wb = __int_as_float(rb.y);
            float fa[8], fb[8];
            h8_to_f8(ya, fa); h8_to_f8(yb, fb);
            #pragma unroll
            for (int j = 0; j < 8; ++j) accv[j] += wa * fa[j];
            #pragma unroll
            for (int j = 0; j < 8; ++j) accv[j] += wb * fb[j];
        }
        for (; i + 8 <= end; i += 8) {            // single batch
            int2 r = sorted[i + g];
            float4 yv = *(const float4*)(Y + (r.x & 0x1FFFF) * C + c8 * 8);
            float w = __int_as_float(r.y);
            float f[8]; h8_to_f8(yv, f);
            #pragma unroll
            for (int j = 0; j < 8; ++j) accv[j] += w * f[j];
        }
        int rem = end - i;                        // 0..7 tail
        if (rem > 0) {
            int2 r = sorted[i + (g < rem ? g : 0)];
            float w = (g < rem) ? __int_as_float(r.y) : 0.f;
            float4 yv = *(const float4*)(Y + (r.x & 0x1FFFF) * C + c8 * 8);
            float f[8]; h8_to_f8(yv, f);
            #pragma unroll
            for (int j = 0; j < 8; ++j) accv[j] += w * f[j];
        }
        // overflow backstop (ovn expected 0): only g==0 copies add
        if (g == 0) {
            for (int k = 0; k < ovn; ++k) {
                int4 rr = ovf[k];
                if (rr.y == v) {
                    float4 yv = *(const float4*)(Y + rr.x * C + c8 * 8);
                    float f[8]; h8_to_f8(yv, f);
                    float w = __int_as_float(rr.z);
                    #pragma unroll
                    for (int j = 0; j < 8; ++j) accv[j] += w * f[j];
                }
            }
        }
        // butterfly reduce over g (lanes differing in bits 3..5)
        #pragma unroll
        for (int off = 8; off < 64; off <<= 1)
            #pragma unroll
            for (int j = 0; j < 8; ++j)
                accv[j] += __shfl_xor(accv[j], off, 64);
        if (g == 0) {
            float4 o0 = make_float4(accv[0] + bb0.x, accv[1] + bb0.y,
                                    accv[2] + bb0.z, accv[3] + bb0.w);
            float4 o1 = make_float4(accv[4] + bb1.x, accv[5] + bb1.y,
                                    accv[6] + bb1.z, accv[7] + bb1.w);
            *(float4*)(out + (size_t)v * C + c8 * 8)     = o0;
            *(float4*)(out + (size_t)v * C + c8 * 8 + 4) = o1;
        }
    }
}

// ===========================================================================
// Fallback (ws too small): fp32 Y + bias init + fp32 atomic scatter
// ===========================================================================
__global__ __launch_bounds__(256) void xw_kernel(const float* __restrict__ X,
                                                 const float* __restrict__ W,
                                                 float* __restrict__ Y) {
    __shared__ float Ws[64][64];
    const float4* W4 = (const float4*)W;
    float4* Ws4 = (float4*)&Ws[0][0];
    #pragma unroll
    for (int i = 0; i < 4; ++i)
        Ws4[threadIdx.x + 256 * i] = W4[threadIdx.x + 256 * i];
    __syncthreads();
    const int wave = threadIdx.x >> 6;
    const int lane = threadIdx.x & 63;
    for (int row = blockIdx.x * 4 + wave; row < V; row += gridDim.x * 4) {
        float xv = X[row * C + lane];
        float acc = 0.f;
        #pragma unroll
        for (int k = 0; k < C; ++k)
            acc += __shfl(xv, k, 64) * Ws[k][lane];
        Y[row * C + lane] = acc;
    }
}

__global__ __launch_bounds__(256) void init_out_kernel(const float* __restrict__ b,
                                                       float4* __restrict__ out4) {
    int tid = blockIdx.x * 256 + threadIdx.x;
    const int n4 = V * (C / 4);
    if (tid < n4) {
        const float4* b4 = (const float4*)b;
        out4[tid] = b4[tid & 15];
    }
}

__global__ __launch_bounds__(256) void scatter_kernel(const int*   __restrict__ esrc,
                                                      const int*   __restrict__ edst,
                                                      const float* __restrict__ ew,
                                                      const float* __restrict__ Y,
                                                      float*       __restrict__ out) {
    unsigned tid = blockIdx.x * 256u + threadIdx.x;
    unsigned e = tid >> 4;
    if (e >= (unsigned)E) return;
    int g = (tid & 15) * 4;
    int   s  = esrc[e];
    int   d  = edst[e];
    float we = ew[e];
    float4 y = *(const float4*)(Y + s * C + g);
    float* o = out + (size_t)d * C + g;
    atomicAdd(o + 0, we * y.x);
    atomicAdd(o + 1, we * y.y);
    atomicAdd(o + 2, we * y.z);
    atomicAdd(o + 3, we * y.w);
}

extern "C" void kernel_launch(void* const* d_in, const int* in_sizes, int n_in,
                              void* d_out, int out_size, void* d_ws, size_t ws_size,
                              hipStream_t stream) {
    const float* X    = (const float*)d_in[0];
    const int*   esrc = (const int*)  d_in[1];
    const int*   edst = (const int*)  d_in[2];
    const float* ew   = (const float*)d_in[3];
    const float* W    = (const float*)d_in[4];
    const float* b    = (const float*)d_in[5];
    float* out = (float*)d_out;

    char* ws = (char*)d_ws;

    if (ws_size >= WS_NEW) {
        __half* Y     = (__half*)(ws + Y_OFF);
        int2*  binned = (int2*)(ws + BIN_OFF);
        int*   gcnt   = (int*) (ws + GCNT_OFF);
        int*   oc     = (int*) (ws + OC_OFF);
        int4*  ovf    = (int4*)(ws + OVF_OFF);

        zero_kernel<<<1, 256, 0, stream>>>(gcnt, oc);
        xwbin_kernel<<<FUSE_GRID, FUSE_T, 0, stream>>>(X, W, Y, esrc, edst, ew,
                                                       gcnt, binned, oc, ovf);
        bucket_gather_kernel<<<NBKT, 512, 0, stream>>>(gcnt, binned, oc, ovf, Y, b, out);
    } else {
        float* Y = (float*)(ws + Y_OFF);
        xw_kernel<<<1024, 256, 0, stream>>>(X, W, Y);
        init_out_kernel<<<(V * (C / 4) + 255) / 256, 256, 0, stream>>>(b, (float4*)out);
        scatter_kernel<<<(E * 16 + 255) / 256, 256, 0, stream>>>(esrc, edst, ew, Y, out);
    }
}

// Round 6
// 142.996 us; speedup vs baseline: 1.0420x; 1.0420x over previous
//
#include <hip/hip_runtime.h>
#include <hip/hip_fp16.h>

// GraphConv: out = segment_sum(w * X[src] -> dst) @ W + b
// = gather of w * (X@W)[src] per dst (matmul distributes over segment-sum).
// Round 15: r14 retry — __builtin_nontemporal_load requires scalar or
// ext_vector_type pointers (HIP_vector_type float4/int2 rejected). Route
// through ext_vector aliases (f32x4, i32x2); semantics identical.
// Structure = exact r10 (verified 137.9us) + NT hints on read-once/
// write-once streams (out stores, binned+edge reads, X reads) to keep L2
// capacity for hot Y rows in the gather's random-row critical path.
//
// V=100000, E=1250000, C=64, fp32 in/out.

constexpr int V = 100000;
constexpr int E = 1250000;
constexpr int C = 64;

constexpr int NBKT = 1024;        // dst buckets
constexpr int VB   = 98;          // vertices per bucket (1024*98 >= V)
constexpr int BCAP = 1536;        // records per bucket (mean 1221, +9 sigma)
constexpr int FL   = 8;           // LDS staging slots per bucket in bin role
constexpr int OVF_CAP = 16384;

// ---------------- workspace layout (bytes) ----------------
constexpr size_t Y_OFF    = 0;           // V*C*2 = 12,800,000 (fp16)
constexpr size_t BIN_OFF  = 12800000;    // NBKT*BCAP*8 = 12,582,912
constexpr size_t GCNT_OFF = 25382912;    // NBKT*4 = 4,096
constexpr size_t OC_OFF   = 25387008;    // 16  (contiguous after gcnt)
constexpr size_t OVF_OFF  = 25387024;    // OVF_CAP*16 = 262,144
constexpr size_t WS_NEW   = 25649168;

using bf16x8 = __attribute__((ext_vector_type(8))) short;
using f32x4  = __attribute__((ext_vector_type(4))) float;
using i32x2  = __attribute__((ext_vector_type(2))) int;

__device__ __forceinline__ short f2bf(float x) {          // RNE float->bf16 bits
    unsigned u = __float_as_uint(x);
    unsigned r = u + 0x7fffu + ((u >> 16) & 1u);
    return (short)(r >> 16);
}
__device__ __forceinline__ float bf2f(short h) {
    return __uint_as_float(((unsigned)(unsigned short)h) << 16);
}

// ---------------------------------------------------------------------------
// Tiny zero kernel: gcnt (1024 ints) + oc. ~1.5us, stream-ordered before the
// fused kernel (measured faster than a hipMemsetAsync fill dispatch, r12).
// ---------------------------------------------------------------------------
__global__ __launch_bounds__(256) void zero_kernel(int* __restrict__ gcnt,
                                                   int* __restrict__ oc) {
    int i = threadIdx.x;
    #pragma unroll
    for (int j = 0; j < NBKT / 256; ++j) gcnt[i + j * 256] = 0;
    if (i == 0) *oc = 0;
}

// ---------------------------------------------------------------------------
// Fused XW + bin kernel (r10, verified). 512-thread blocks, grid = 261x5:
// slots 0-2 -> xw role (782 blocks x 8 waves = 6256 chunks >= 6250),
// slots 3-4 -> bin role (512 blocks). Interleave keeps both roles resident
// on every CU so the bin phase hides behind xw.
// ---------------------------------------------------------------------------
constexpr int FUSE_T    = 512;
constexpr int XWB       = 782;           // xw role blocks
constexpr int BINB      = 512;           // bin role blocks
constexpr int FUSE_GRID = 261 * 5;       // 1305 (last group partially idle)

__global__ __launch_bounds__(FUSE_T) void xwbin_kernel(
        const float* __restrict__ X,
        const float* __restrict__ W,
        __half*      __restrict__ Y,
        const int*   __restrict__ esrc,
        const int*   __restrict__ edst,
        const float* __restrict__ ew,
        int*  __restrict__ gcnt,
        int2* __restrict__ binned,
        int*  __restrict__ oc,
        int4* __restrict__ ovf) {
    __shared__ union {
        struct { short Whi[64 * 72]; short Wlo[64 * 72]; } xw;   // 18.4 KB
        struct { int2 stage[NBKT][FL]; int lcnt[NBKT]; } bin;    // 68 KB
    } u;

    const int grp  = blockIdx.x / 5;
    const int slot = blockIdx.x % 5;

    if (slot < 3) {
        // ------------------------------ XW role ------------------------------
        const int xb = grp * 3 + slot;
        if (xb >= XWB) return;

        for (int idx = threadIdx.x; idx < 4096; idx += FUSE_T) {
            int k = idx >> 6, c = idx & 63;
            float w  = W[idx];
            short hi = f2bf(w);
            short lo = f2bf(w - bf2f(hi));
            u.xw.Whi[c * 72 + k] = hi;
            u.xw.Wlo[c * 72 + k] = lo;
        }
        __syncthreads();

        const int wave = threadIdx.x >> 6;       // 0..7
        const int lane = threadIdx.x & 63;
        const int m = lane & 15;
        const int q = lane >> 4;

        bf16x8 bhi[4][2], blo[4][2];
        #pragma unroll
        for (int t = 0; t < 4; ++t)
            #pragma unroll
            for (int h = 0; h < 2; ++h) {
                int o = (t * 16 + m) * 72 + h * 32 + q * 8;
                bhi[t][h] = *(const bf16x8*)&u.xw.Whi[o];
                blo[t][h] = *(const bf16x8*)&u.xw.Wlo[o];
            }

        const int chunk = xb * 8 + wave;
        if (chunk >= V / 16) return;
        {
            const float* xp = X + (chunk * 16 + m) * 64 + q * 8;
            bf16x8 ahi[2], alo[2];
            #pragma unroll
            for (int h = 0; h < 2; ++h) {
                f32x4 f0 = __builtin_nontemporal_load((const f32x4*)(xp + h * 32));
                f32x4 f1 = __builtin_nontemporal_load((const f32x4*)(xp + h * 32 + 4));
                float f[8] = {f0[0], f0[1], f0[2], f0[3], f1[0], f1[1], f1[2], f1[3]};
                #pragma unroll
                for (int j = 0; j < 8; ++j) {
                    short hi = f2bf(f[j]);
                    ahi[h][j] = hi;
                    alo[h][j] = f2bf(f[j] - bf2f(hi));
                }
            }
            #pragma unroll
            for (int t = 0; t < 4; ++t) {
                f32x4 acc = {0.f, 0.f, 0.f, 0.f};
                #pragma unroll
                for (int h = 0; h < 2; ++h) {
                    acc = __builtin_amdgcn_mfma_f32_16x16x32_bf16(ahi[h], bhi[t][h], acc, 0, 0, 0);
                    acc = __builtin_amdgcn_mfma_f32_16x16x32_bf16(alo[h], bhi[t][h], acc, 0, 0, 0);
                    acc = __builtin_amdgcn_mfma_f32_16x16x32_bf16(ahi[h], blo[t][h], acc, 0, 0, 0);
                }
                #pragma unroll
                for (int i = 0; i < 4; ++i) {
                    int row = chunk * 16 + q * 4 + i;
                    Y[row * 64 + t * 16 + m] = __float2half(acc[i]);
                }
            }
        }
    } else {
        // ------------------------------ bin role -----------------------------
        const int bb = grp * 2 + (slot - 3);
        if (bb >= BINB) return;

        for (int i = threadIdx.x; i < NBKT; i += FUSE_T) u.bin.lcnt[i] = 0;
        __syncthreads();

        const int iters = (E + BINB * FUSE_T - 1) / (BINB * FUSE_T);   // 5
        for (int it = 0; it < iters; ++it) {
            int e = (it * BINB + bb) * FUSE_T + threadIdx.x;
            if (e < E) {
                int d = __builtin_nontemporal_load(edst + e);
                int s = __builtin_nontemporal_load(esrc + e);
                float w = __builtin_nontemporal_load(ew + e);
                int bkt = d / VB;
                int ld  = d - bkt * VB;
                int2 rec = make_int2((ld << 17) | s, __float_as_int(w));
                int pos = atomicAdd(&u.bin.lcnt[bkt], 1);
                if (pos < FL) {
                    u.bin.stage[bkt][pos] = rec;
                } else {                              // staging spill (~0.1%)
                    int g = atomicAdd(&gcnt[bkt], 1);
                    if (g < BCAP) binned[bkt * BCAP + g] = rec;
                    else { int p = atomicAdd(oc, 1);
                           if (p < OVF_CAP) ovf[p] = make_int4(s, d, __float_as_int(w), 0); }
                }
            }
        }
        __syncthreads();
        // final flush: one thread per bucket — contiguous burst each
        for (int b = threadIdx.x; b < NBKT; b += FUSE_T) {
            int n = u.bin.lcnt[b]; n = n < FL ? n : FL;
            if (n > 0) {
                int g = atomicAdd(&gcnt[b], n);
                for (int i = 0; i < n; ++i) {
                    int gi = g + i;
                    int2 r = u.bin.stage[b][i];
                    if (gi < BCAP) binned[b * BCAP + gi] = r;
                    else { int s = r.x & 0x1FFFF; int ld = r.x >> 17;
                           int p = atomicAdd(oc, 1);
                           if (p < OVF_CAP) ovf[p] = make_int4(s, b * VB + ld, r.y, 0); }
                }
            }
        }
    }
}

// ---------------------------------------------------------------------------
// Bucket gather: r10-verified version + NT hints. One 512-thread block per
// bucket (27 KB LDS -> 32 waves/CU). Counting-sort the bucket's records in
// LDS, then per-vertex register gather (wave per vertex, lane = channel,
// fp16 Y, fused bias) with 8 outstanding Y loads. Overflow list folded in.
// binned reads and out writes are nontemporal (read/write-once) so L2
// capacity stays with hot Y rows.
// ---------------------------------------------------------------------------
__global__ __launch_bounds__(512) void bucket_gather_kernel(const int*  __restrict__ gcnt,
                                                            const int2* __restrict__ binned,
                                                            const int*  __restrict__ oc,
                                                            const int4* __restrict__ ovf,
                                                            const __half* __restrict__ Y,
                                                            const float* __restrict__ bias,
                                                            float* __restrict__ out) {
    __shared__ int2 raw[BCAP];           // 12 KB
    __shared__ int2 sorted[BCAP];        // 12 KB
    __shared__ int  cnt[VB];
    __shared__ int  pre[VB];
    __shared__ int  cur[VB];
    __shared__ int  buf[128];

    const int tid = threadIdx.x;
    const int b   = blockIdx.x;
    int n = gcnt[b]; n = n < BCAP ? n : BCAP;

    for (int i = tid; i < VB; i += 512) cnt[i] = 0;
    __syncthreads();

    const int2* src = binned + b * BCAP;
    for (int i = tid; i < n; i += 512) {
        i32x2 rv = __builtin_nontemporal_load((const i32x2*)(src + i));
        int2 r = make_int2(rv[0], rv[1]);
        raw[i] = r;
        atomicAdd(&cnt[r.x >> 17], 1);
    }
    __syncthreads();

    // exclusive scan of cnt[0..VB) over first 128 threads (VB <= 128)
    int x = 0;
    if (tid < 128) { x = (tid < VB) ? cnt[tid] : 0; buf[tid] = x; }
    __syncthreads();
    #pragma unroll
    for (int ofs = 1; ofs < 128; ofs <<= 1) {
        int t = 0;
        if (tid < 128 && tid >= ofs) t = buf[tid - ofs];
        __syncthreads();
        if (tid < 128) buf[tid] += t;
        __syncthreads();
    }
    if (tid < VB) { int ex = buf[tid] - x; pre[tid] = ex; cur[tid] = ex; }
    __syncthreads();

    for (int i = tid; i < n; i += 512) {
        int2 r = raw[i];
        int ld = r.x >> 17;
        int p = atomicAdd(&cur[ld], 1);
        sorted[p] = r;
    }
    __syncthreads();

    const int lane = tid & 63;
    const int wv   = tid >> 6;           // 0..7
    float bias_l = bias[lane];
    int ovn = *oc; ovn = ovn < OVF_CAP ? ovn : OVF_CAP;   // expected 0

    for (int ld = wv; ld < VB; ld += 8) {
        int v = b * VB + ld;
        if (v >= V) break;
        int beg = pre[ld];
        int end = beg + cnt[ld];
        float acc = 0.f;
        int i = beg;
        for (; i + 8 <= end; i += 8) {           // 8 outstanding Y-row loads
            int2 r0 = sorted[i],     r1 = sorted[i + 1];
            int2 r2 = sorted[i + 2], r3 = sorted[i + 3];
            int2 r4 = sorted[i + 4], r5 = sorted[i + 5];
            int2 r6 = sorted[i + 6], r7 = sorted[i + 7];
            float y0 = __half2float(Y[(r0.x & 0x1FFFF) * C + lane]);
            float y1 = __half2float(Y[(r1.x & 0x1FFFF) * C + lane]);
            float y2 = __half2float(Y[(r2.x & 0x1FFFF) * C + lane]);
            float y3 = __half2float(Y[(r3.x & 0x1FFFF) * C + lane]);
            float y4 = __half2float(Y[(r4.x & 0x1FFFF) * C + lane]);
            float y5 = __half2float(Y[(r5.x & 0x1FFFF) * C + lane]);
            float y6 = __half2float(Y[(r6.x & 0x1FFFF) * C + lane]);
            float y7 = __half2float(Y[(r7.x & 0x1FFFF) * C + lane]);
            acc += __int_as_float(r0.y) * y0;
            acc += __int_as_float(r1.y) * y1;
            acc += __int_as_float(r2.y) * y2;
            acc += __int_as_float(r3.y) * y3;
            acc += __int_as_float(r4.y) * y4;
            acc += __int_as_float(r5.y) * y5;
            acc += __int_as_float(r6.y) * y6;
            acc += __int_as_float(r7.y) * y7;
        }
        for (; i + 4 <= end; i += 4) {
            int2 r0 = sorted[i], r1 = sorted[i + 1], r2 = sorted[i + 2], r3 = sorted[i + 3];
            float y0 = __half2float(Y[(r0.x & 0x1FFFF) * C + lane]);
            float y1 = __half2float(Y[(r1.x & 0x1FFFF) * C + lane]);
            float y2 = __half2float(Y[(r2.x & 0x1FFFF) * C + lane]);
            float y3 = __half2float(Y[(r3.x & 0x1FFFF) * C + lane]);
            acc += __int_as_float(r0.y) * y0;
            acc += __int_as_float(r1.y) * y1;
            acc += __int_as_float(r2.y) * y2;
            acc += __int_as_float(r3.y) * y3;
        }
        for (; i < end; ++i) {
            int2 rr = sorted[i];
            acc += __int_as_float(rr.y) * __half2float(Y[(rr.x & 0x1FFFF) * C + lane]);
        }
        // overflow backstop (ovn expected 0)
        for (int k = 0; k < ovn; ++k) {
            int4 rr = ovf[k];
            if (rr.y == v)
                acc += __int_as_float(rr.z) * __half2float(Y[rr.x * C + lane]);
        }
        __builtin_nontemporal_store(acc + bias_l, out + (size_t)v * C + lane);
    }
}

// ===========================================================================
// Fallback (ws too small): fp32 Y + bias init + fp32 atomic scatter
// ===========================================================================
__global__ __launch_bounds__(256) void xw_kernel(const float* __restrict__ X,
                                                 const float* __restrict__ W,
                                                 float* __restrict__ Y) {
    __shared__ float Ws[64][64];
    const float4* W4 = (const float4*)W;
    float4* Ws4 = (float4*)&Ws[0][0];
    #pragma unroll
    for (int i = 0; i < 4; ++i)
        Ws4[threadIdx.x + 256 * i] = W4[threadIdx.x + 256 * i];
    __syncthreads();
    const int wave = threadIdx.x >> 6;
    const int lane = threadIdx.x & 63;
    for (int row = blockIdx.x * 4 + wave; row < V; row += gridDim.x * 4) {
        float xv = X[row * C + lane];
        float acc = 0.f;
        #pragma unroll
        for (int k = 0; k < C; ++k)
            acc += __shfl(xv, k, 64) * Ws[k][lane];
        Y[row * C + lane] = acc;
    }
}

__global__ __launch_bounds__(256) void init_out_kernel(const float* __restrict__ b,
                                                       float4* __restrict__ out4) {
    int tid = blockIdx.x * 256 + threadIdx.x;
    const int n4 = V * (C / 4);
    if (tid < n4) {
        const float4* b4 = (const float4*)b;
        out4[tid] = b4[tid & 15];
    }
}

__global__ __launch_bounds__(256) void scatter_kernel(const int*   __restrict__ esrc,
                                                      const int*   __restrict__ edst,
                                                      const float* __restrict__ ew,
                                                      const float* __restrict__ Y,
                                                      float*       __restrict__ out) {
    unsigned tid = blockIdx.x * 256u + threadIdx.x;
    unsigned e = tid >> 4;
    if (e >= (unsigned)E) return;
    int g = (tid & 15) * 4;
    int   s  = esrc[e];
    int   d  = edst[e];
    float we = ew[e];
    float4 y = *(const float4*)(Y + s * C + g);
    float* o = out + (size_t)d * C + g;
    atomicAdd(o + 0, we * y.x);
    atomicAdd(o + 1, we * y.y);
    atomicAdd(o + 2, we * y.z);
    atomicAdd(o + 3, we * y.w);
}

extern "C" void kernel_launch(void* const* d_in, const int* in_sizes, int n_in,
                              void* d_out, int out_size, void* d_ws, size_t ws_size,
                              hipStream_t stream) {
    const float* X    = (const float*)d_in[0];
    const int*   esrc = (const int*)  d_in[1];
    const int*   edst = (const int*)  d_in[2];
    const float* ew   = (const float*)d_in[3];
    const float* W    = (const float*)d_in[4];
    const float* b    = (const float*)d_in[5];
    float* out = (float*)d_out;

    char* ws = (char*)d_ws;

    if (ws_size >= WS_NEW) {
        __half* Y     = (__half*)(ws + Y_OFF);
        int2*  binned = (int2*)(ws + BIN_OFF);
        int*   gcnt   = (int*) (ws + GCNT_OFF);
        int*   oc     = (int*) (ws + OC_OFF);
        int4*  ovf    = (int4*)(ws + OVF_OFF);

        zero_kernel<<<1, 256, 0, stream>>>(gcnt, oc);
        xwbin_kernel<<<FUSE_GRID, FUSE_T, 0, stream>>>(X, W, Y, esrc, edst, ew,
                                                       gcnt, binned, oc, ovf);
        bucket_gather_kernel<<<NBKT, 512, 0, stream>>>(gcnt, binned, oc, ovf, Y, b, out);
    } else {
        float* Y = (float*)(ws + Y_OFF);
        xw_kernel<<<1024, 256, 0, stream>>>(X, W, Y);
        init_out_kernel<<<(V * (C / 4) + 255) / 256, 256, 0, stream>>>(b, (float4*)out);
        scatter_kernel<<<(E * 16 + 255) / 256, 256, 0, stream>>>(esrc, edst, ew, Y, out);
    }
}

// Round 7
// 142.121 us; speedup vs baseline: 1.0484x; 1.0062x over previous
//
#include <hip/hip_runtime.h>
#include <hip/hip_fp16.h>

// GraphConv: out = segment_sum(w * X[src] -> dst) @ W + b
// = gather of w * (X@W)[src] per dst (matmul distributes over segment-sum).
// Round 16: FINAL — revert r15's NT hints (+5.1us: nt demotes L2+L3 lines;
// no capacity pressure existed to relieve at 63MB working set vs 256MB L3).
// This is the exact r10 structure, the measured optimum (137.9us):
//   zero_kernel (1.5us) -> xwbin (role-split: 782 xw-blocks MFMA X@W->fp16 Y
//   || 512 bin-blocks LDS-staged edge binning) -> bucket_gather (counting
//   sort + register gather, 8 outstanding Y loads).
// Ledger: r11 LDS-atomic gather +397us (MLP collapse, VGPR=20 proof);
// r12 memset zeroing +2.3; r13 vectorized gather +11; r15 NT +5.1.
// Remaining time: ~87us harness poison-fill tax + ~50us kernels near their
// respective stream-BW / random-gather cache floors.
//
// V=100000, E=1250000, C=64, fp32 in/out.

constexpr int V = 100000;
constexpr int E = 1250000;
constexpr int C = 64;

constexpr int NBKT = 1024;        // dst buckets
constexpr int VB   = 98;          // vertices per bucket (1024*98 >= V)
constexpr int BCAP = 1536;        // records per bucket (mean 1221, +9 sigma)
constexpr int FL   = 8;           // LDS staging slots per bucket in bin role
constexpr int OVF_CAP = 16384;

// ---------------- workspace layout (bytes) ----------------
constexpr size_t Y_OFF    = 0;           // V*C*2 = 12,800,000 (fp16)
constexpr size_t BIN_OFF  = 12800000;    // NBKT*BCAP*8 = 12,582,912
constexpr size_t GCNT_OFF = 25382912;    // NBKT*4 = 4,096
constexpr size_t OC_OFF   = 25387008;    // 16
constexpr size_t OVF_OFF  = 25387024;    // OVF_CAP*16 = 262,144
constexpr size_t WS_NEW   = 25649168;

using bf16x8 = __attribute__((ext_vector_type(8))) short;
using f32x4  = __attribute__((ext_vector_type(4))) float;

__device__ __forceinline__ short f2bf(float x) {          // RNE float->bf16 bits
    unsigned u = __float_as_uint(x);
    unsigned r = u + 0x7fffu + ((u >> 16) & 1u);
    return (short)(r >> 16);
}
__device__ __forceinline__ float bf2f(short h) {
    return __uint_as_float(((unsigned)(unsigned short)h) << 16);
}

// ---------------------------------------------------------------------------
// Tiny zero kernel: gcnt (1024 ints) + oc. ~1.5us, stream-ordered before the
// fused kernel (measured faster than a hipMemsetAsync fill dispatch, r12).
// ---------------------------------------------------------------------------
__global__ __launch_bounds__(256) void zero_kernel(int* __restrict__ gcnt,
                                                   int* __restrict__ oc) {
    int i = threadIdx.x;
    #pragma unroll
    for (int j = 0; j < NBKT / 256; ++j) gcnt[i + j * 256] = 0;
    if (i == 0) *oc = 0;
}

// ---------------------------------------------------------------------------
// Fused XW + bin kernel (r10, verified). 512-thread blocks, grid = 261x5:
// slots 0-2 -> xw role (782 blocks x 8 waves = 6256 chunks >= 6250),
// slots 3-4 -> bin role (512 blocks). Interleave keeps both roles resident
// on every CU so the bin phase hides behind xw.
// ---------------------------------------------------------------------------
constexpr int FUSE_T    = 512;
constexpr int XWB       = 782;           // xw role blocks
constexpr int BINB      = 512;           // bin role blocks
constexpr int FUSE_GRID = 261 * 5;       // 1305 (last group partially idle)

__global__ __launch_bounds__(FUSE_T) void xwbin_kernel(
        const float* __restrict__ X,
        const float* __restrict__ W,
        __half*      __restrict__ Y,
        const int*   __restrict__ esrc,
        const int*   __restrict__ edst,
        const float* __restrict__ ew,
        int*  __restrict__ gcnt,
        int2* __restrict__ binned,
        int*  __restrict__ oc,
        int4* __restrict__ ovf) {
    __shared__ union {
        struct { short Whi[64 * 72]; short Wlo[64 * 72]; } xw;   // 18.4 KB
        struct { int2 stage[NBKT][FL]; int lcnt[NBKT]; } bin;    // 68 KB
    } u;

    const int grp  = blockIdx.x / 5;
    const int slot = blockIdx.x % 5;

    if (slot < 3) {
        // ------------------------------ XW role ------------------------------
        const int xb = grp * 3 + slot;
        if (xb >= XWB) return;

        for (int idx = threadIdx.x; idx < 4096; idx += FUSE_T) {
            int k = idx >> 6, c = idx & 63;
            float w  = W[idx];
            short hi = f2bf(w);
            short lo = f2bf(w - bf2f(hi));
            u.xw.Whi[c * 72 + k] = hi;
            u.xw.Wlo[c * 72 + k] = lo;
        }
        __syncthreads();

        const int wave = threadIdx.x >> 6;       // 0..7
        const int lane = threadIdx.x & 63;
        const int m = lane & 15;
        const int q = lane >> 4;

        bf16x8 bhi[4][2], blo[4][2];
        #pragma unroll
        for (int t = 0; t < 4; ++t)
            #pragma unroll
            for (int h = 0; h < 2; ++h) {
                int o = (t * 16 + m) * 72 + h * 32 + q * 8;
                bhi[t][h] = *(const bf16x8*)&u.xw.Whi[o];
                blo[t][h] = *(const bf16x8*)&u.xw.Wlo[o];
            }

        const int chunk = xb * 8 + wave;
        if (chunk >= V / 16) return;
        {
            const float* xp = X + (chunk * 16 + m) * 64 + q * 8;
            bf16x8 ahi[2], alo[2];
            #pragma unroll
            for (int h = 0; h < 2; ++h) {
                float4 f0 = *(const float4*)(xp + h * 32);
                float4 f1 = *(const float4*)(xp + h * 32 + 4);
                float f[8] = {f0.x, f0.y, f0.z, f0.w, f1.x, f1.y, f1.z, f1.w};
                #pragma unroll
                for (int j = 0; j < 8; ++j) {
                    short hi = f2bf(f[j]);
                    ahi[h][j] = hi;
                    alo[h][j] = f2bf(f[j] - bf2f(hi));
                }
            }
            #pragma unroll
            for (int t = 0; t < 4; ++t) {
                f32x4 acc = {0.f, 0.f, 0.f, 0.f};
                #pragma unroll
                for (int h = 0; h < 2; ++h) {
                    acc = __builtin_amdgcn_mfma_f32_16x16x32_bf16(ahi[h], bhi[t][h], acc, 0, 0, 0);
                    acc = __builtin_amdgcn_mfma_f32_16x16x32_bf16(alo[h], bhi[t][h], acc, 0, 0, 0);
                    acc = __builtin_amdgcn_mfma_f32_16x16x32_bf16(ahi[h], blo[t][h], acc, 0, 0, 0);
                }
                #pragma unroll
                for (int i = 0; i < 4; ++i) {
                    int row = chunk * 16 + q * 4 + i;
                    Y[row * 64 + t * 16 + m] = __float2half(acc[i]);
                }
            }
        }
    } else {
        // ------------------------------ bin role -----------------------------
        const int bb = grp * 2 + (slot - 3);
        if (bb >= BINB) return;

        for (int i = threadIdx.x; i < NBKT; i += FUSE_T) u.bin.lcnt[i] = 0;
        __syncthreads();

        const int iters = (E + BINB * FUSE_T - 1) / (BINB * FUSE_T);   // 5
        for (int it = 0; it < iters; ++it) {
            int e = (it * BINB + bb) * FUSE_T + threadIdx.x;
            if (e < E) {
                int d = edst[e];
                int s = esrc[e];
                float w = ew[e];
                int bkt = d / VB;
                int ld  = d - bkt * VB;
                int2 rec = make_int2((ld << 17) | s, __float_as_int(w));
                int pos = atomicAdd(&u.bin.lcnt[bkt], 1);
                if (pos < FL) {
                    u.bin.stage[bkt][pos] = rec;
                } else {                              // staging spill (~0.1%)
                    int g = atomicAdd(&gcnt[bkt], 1);
                    if (g < BCAP) binned[bkt * BCAP + g] = rec;
                    else { int p = atomicAdd(oc, 1);
                           if (p < OVF_CAP) ovf[p] = make_int4(s, d, __float_as_int(w), 0); }
                }
            }
        }
        __syncthreads();
        // final flush: one thread per bucket — contiguous burst each
        for (int b = threadIdx.x; b < NBKT; b += FUSE_T) {
            int n = u.bin.lcnt[b]; n = n < FL ? n : FL;
            if (n > 0) {
                int g = atomicAdd(&gcnt[b], n);
                for (int i = 0; i < n; ++i) {
                    int gi = g + i;
                    int2 r = u.bin.stage[b][i];
                    if (gi < BCAP) binned[b * BCAP + gi] = r;
                    else { int s = r.x & 0x1FFFF; int ld = r.x >> 17;
                           int p = atomicAdd(oc, 1);
                           if (p < OVF_CAP) ovf[p] = make_int4(s, b * VB + ld, r.y, 0); }
                }
            }
        }
    }
}

// ---------------------------------------------------------------------------
// Bucket gather: r10-verified version. One 512-thread block per bucket
// (27 KB LDS -> 32 waves/CU). Counting-sort the bucket's records in LDS,
// then per-vertex register gather (wave per vertex, lane = channel, fp16 Y,
// fused bias) with 8 outstanding Y loads. Overflow list folded in.
// ---------------------------------------------------------------------------
__global__ __launch_bounds__(512) void bucket_gather_kernel(const int*  __restrict__ gcnt,
                                                            const int2* __restrict__ binned,
                                                            const int*  __restrict__ oc,
                                                            const int4* __restrict__ ovf,
                                                            const __half* __restrict__ Y,
                                                            const float* __restrict__ bias,
                                                            float* __restrict__ out) {
    __shared__ int2 raw[BCAP];           // 12 KB
    __shared__ int2 sorted[BCAP];        // 12 KB
    __shared__ int  cnt[VB];
    __shared__ int  pre[VB];
    __shared__ int  cur[VB];
    __shared__ int  buf[128];

    const int tid = threadIdx.x;
    const int b   = blockIdx.x;
    int n = gcnt[b]; n = n < BCAP ? n : BCAP;

    for (int i = tid; i < VB; i += 512) cnt[i] = 0;
    __syncthreads();

    const int2* src = binned + b * BCAP;
    for (int i = tid; i < n; i += 512) {
        int2 r = src[i];
        raw[i] = r;
        atomicAdd(&cnt[r.x >> 17], 1);
    }
    __syncthreads();

    // exclusive scan of cnt[0..VB) over first 128 threads (VB <= 128)
    int x = 0;
    if (tid < 128) { x = (tid < VB) ? cnt[tid] : 0; buf[tid] = x; }
    __syncthreads();
    #pragma unroll
    for (int ofs = 1; ofs < 128; ofs <<= 1) {
        int t = 0;
        if (tid < 128 && tid >= ofs) t = buf[tid - ofs];
        __syncthreads();
        if (tid < 128) buf[tid] += t;
        __syncthreads();
    }
    if (tid < VB) { int ex = buf[tid] - x; pre[tid] = ex; cur[tid] = ex; }
    __syncthreads();

    for (int i = tid; i < n; i += 512) {
        int2 r = raw[i];
        int ld = r.x >> 17;
        int p = atomicAdd(&cur[ld], 1);
        sorted[p] = r;
    }
    __syncthreads();

    const int lane = tid & 63;
    const int wv   = tid >> 6;           // 0..7
    float bias_l = bias[lane];
    int ovn = *oc; ovn = ovn < OVF_CAP ? ovn : OVF_CAP;   // expected 0

    for (int ld = wv; ld < VB; ld += 8) {
        int v = b * VB + ld;
        if (v >= V) break;
        int beg = pre[ld];
        int end = beg + cnt[ld];
        float acc = 0.f;
        int i = beg;
        for (; i + 8 <= end; i += 8) {           // 8 outstanding Y-row loads
            int2 r0 = sorted[i],     r1 = sorted[i + 1];
            int2 r2 = sorted[i + 2], r3 = sorted[i + 3];
            int2 r4 = sorted[i + 4], r5 = sorted[i + 5];
            int2 r6 = sorted[i + 6], r7 = sorted[i + 7];
            float y0 = __half2float(Y[(r0.x & 0x1FFFF) * C + lane]);
            float y1 = __half2float(Y[(r1.x & 0x1FFFF) * C + lane]);
            float y2 = __half2float(Y[(r2.x & 0x1FFFF) * C + lane]);
            float y3 = __half2float(Y[(r3.x & 0x1FFFF) * C + lane]);
            float y4 = __half2float(Y[(r4.x & 0x1FFFF) * C + lane]);
            float y5 = __half2float(Y[(r5.x & 0x1FFFF) * C + lane]);
            float y6 = __half2float(Y[(r6.x & 0x1FFFF) * C + lane]);
            float y7 = __half2float(Y[(r7.x & 0x1FFFF) * C + lane]);
            acc += __int_as_float(r0.y) * y0;
            acc += __int_as_float(r1.y) * y1;
            acc += __int_as_float(r2.y) * y2;
            acc += __int_as_float(r3.y) * y3;
            acc += __int_as_float(r4.y) * y4;
            acc += __int_as_float(r5.y) * y5;
            acc += __int_as_float(r6.y) * y6;
            acc += __int_as_float(r7.y) * y7;
        }
        for (; i + 4 <= end; i += 4) {
            int2 r0 = sorted[i], r1 = sorted[i + 1], r2 = sorted[i + 2], r3 = sorted[i + 3];
            float y0 = __half2float(Y[(r0.x & 0x1FFFF) * C + lane]);
            float y1 = __half2float(Y[(r1.x & 0x1FFFF) * C + lane]);
            float y2 = __half2float(Y[(r2.x & 0x1FFFF) * C + lane]);
            float y3 = __half2float(Y[(r3.x & 0x1FFFF) * C + lane]);
            acc += __int_as_float(r0.y) * y0;
            acc += __int_as_float(r1.y) * y1;
            acc += __int_as_float(r2.y) * y2;
            acc += __int_as_float(r3.y) * y3;
        }
        for (; i < end; ++i) {
            int2 rr = sorted[i];
            acc += __int_as_float(rr.y) * __half2float(Y[(rr.x & 0x1FFFF) * C + lane]);
        }
        // overflow backstop (ovn expected 0)
        for (int k = 0; k < ovn; ++k) {
            int4 rr = ovf[k];
            if (rr.y == v)
                acc += __int_as_float(rr.z) * __half2float(Y[rr.x * C + lane]);
        }
        out[v * C + lane] = acc + bias_l;
    }
}

// ===========================================================================
// Fallback (ws too small): fp32 Y + bias init + fp32 atomic scatter
// ===========================================================================
__global__ __launch_bounds__(256) void xw_kernel(const float* __restrict__ X,
                                                 const float* __restrict__ W,
                                                 float* __restrict__ Y) {
    __shared__ float Ws[64][64];
    const float4* W4 = (const float4*)W;
    float4* Ws4 = (float4*)&Ws[0][0];
    #pragma unroll
    for (int i = 0; i < 4; ++i)
        Ws4[threadIdx.x + 256 * i] = W4[threadIdx.x + 256 * i];
    __syncthreads();
    const int wave = threadIdx.x >> 6;
    const int lane = threadIdx.x & 63;
    for (int row = blockIdx.x * 4 + wave; row < V; row += gridDim.x * 4) {
        float xv = X[row * C + lane];
        float acc = 0.f;
        #pragma unroll
        for (int k = 0; k < C; ++k)
            acc += __shfl(xv, k, 64) * Ws[k][lane];
        Y[row * C + lane] = acc;
    }
}

__global__ __launch_bounds__(256) void init_out_kernel(const float* __restrict__ b,
                                                       float4* __restrict__ out4) {
    int tid = blockIdx.x * 256 + threadIdx.x;
    const int n4 = V * (C / 4);
    if (tid < n4) {
        const float4* b4 = (const float4*)b;
        out4[tid] = b4[tid & 15];
    }
}

__global__ __launch_bounds__(256) void scatter_kernel(const int*   __restrict__ esrc,
                                                      const int*   __restrict__ edst,
                                                      const float* __restrict__ ew,
                                                      const float* __restrict__ Y,
                                                      float*       __restrict__ out) {
    unsigned tid = blockIdx.x * 256u + threadIdx.x;
    unsigned e = tid >> 4;
    if (e >= (unsigned)E) return;
    int g = (tid & 15) * 4;
    int   s  = esrc[e];
    int   d  = edst[e];
    float we = ew[e];
    float4 y = *(const float4*)(Y + s * C + g);
    float* o = out + (size_t)d * C + g;
    atomicAdd(o + 0, we * y.x);
    atomicAdd(o + 1, we * y.y);
    atomicAdd(o + 2, we * y.z);
    atomicAdd(o + 3, we * y.w);
}

extern "C" void kernel_launch(void* const* d_in, const int* in_sizes, int n_in,
                              void* d_out, int out_size, void* d_ws, size_t ws_size,
                              hipStream_t stream) {
    const float* X    = (const float*)d_in[0];
    const int*   esrc = (const int*)  d_in[1];
    const int*   edst = (const int*)  d_in[2];
    const float* ew   = (const float*)d_in[3];
    const float* W    = (const float*)d_in[4];
    const float* b    = (const float*)d_in[5];
    float* out = (float*)d_out;

    char* ws = (char*)d_ws;

    if (ws_size >= WS_NEW) {
        __half* Y     = (__half*)(ws + Y_OFF);
        int2*  binned = (int2*)(ws + BIN_OFF);
        int*   gcnt   = (int*) (ws + GCNT_OFF);
        int*   oc     = (int*) (ws + OC_OFF);
        int4*  ovf    = (int4*)(ws + OVF_OFF);

        zero_kernel<<<1, 256, 0, stream>>>(gcnt, oc);
        xwbin_kernel<<<FUSE_GRID, FUSE_T, 0, stream>>>(X, W, Y, esrc, edst, ew,
                                                       gcnt, binned, oc, ovf);
        bucket_gather_kernel<<<NBKT, 512, 0, stream>>>(gcnt, binned, oc, ovf, Y, b, out);
    } else {
        float* Y = (float*)(ws + Y_OFF);
        xw_kernel<<<1024, 256, 0, stream>>>(X, W, Y);
        init_out_kernel<<<(V * (C / 4) + 255) / 256, 256, 0, stream>>>(b, (float4*)out);
        scatter_kernel<<<(E * 16 + 255) / 256, 256, 0, stream>>>(esrc, edst, ew, Y, out);
    }
}